// Round 3
// baseline (575.056 us; speedup 1.0000x reference)
//
#include <hip/hip_runtime.h>
#include <math.h>

// QCQP via FISTA. One 512-thread workgroup per batch; H = P^T P in registers,
// 128 floats/thread. Thread t: r = t>>3 (rows 4r..4r+3), c = t&7 (cols
// 32c..32c+31) -> matvec reduction is 3 intra-wave shfl_xor (c = lane&7),
// SOC projection pairs are thread-local, x ping-pongs in LDS => ONE barrier
// per iteration. LDS x/P rows padded +4 words per 32 to kill 8-way bank
// clashes on the 8-distinct-address b128 reads.

namespace {

constexpr int NDIM = 256;
constexpr int NCON = 128;
constexpr int PITERS = 20;
constexpr int FITERS = 100;
constexpr int PS = 288;     // padded staged-P row stride (words): j -> j + (j>>5)*4

struct Smem {
    float Ps[32 * PS];      // 36,864 B staged P rows (padded)
    float va[PS];           // x ping (padded layout)
    float vb[PS];           // x pong
    float scal[16];
};

// pw[e] = (H x)_{4r+e}; x read from padded LDS buffer xv. No barrier inside.
__device__ __forceinline__ void matvec4(const float (&h)[128],
                                        const float* __restrict__ xv,
                                        int c, float (&pw)[4])
{
    float xr[32];
#pragma unroll
    for (int jj = 0; jj < 8; ++jj) {
        float4 v4 = *(const float4*)(xv + c * 36 + jj * 4);  // pidx(32c+4jj), conflict-free
        xr[jj * 4 + 0] = v4.x; xr[jj * 4 + 1] = v4.y;
        xr[jj * 4 + 2] = v4.z; xr[jj * 4 + 3] = v4.w;
    }
#pragma unroll
    for (int e = 0; e < 4; ++e) pw[e] = 0.0f;
#pragma unroll
    for (int e = 0; e < 4; ++e)
#pragma unroll
        for (int j = 0; j < 32; ++j)
            pw[e] = fmaf(h[e * 32 + j], xr[j], pw[e]);
    // reduce over col-blocks: c = lane&7 -> xor 1,2,4 stays in-wave
#pragma unroll
    for (int e = 0; e < 4; ++e) {
        pw[e] += __shfl_xor(pw[e], 1);
        pw[e] += __shfl_xor(pw[e], 2);
        pw[e] += __shfl_xor(pw[e], 4);
    }
}

__global__ __launch_bounds__(512, 2)
void qcqp_fista(const float* __restrict__ P, const float* __restrict__ q,
                const float* __restrict__ ln_, const float* __restrict__ mu,
                float* __restrict__ out)
{
    __shared__ Smem sm;
    const int b = blockIdx.x;
    const int t = threadIdx.x;
    const int r = t >> 3;        // row block: rows 4r..4r+3
    const int c = t & 7;         // col block: cols 32c..32c+31
    const int wave = t >> 6;
    const int lane = t & 63;
    const int voff = r * 4 + ((r >> 3) << 2);   // pidx(4r): padded float4 slot

    float h[128];
#pragma unroll
    for (int i = 0; i < 128; ++i) h[i] = 0.0f;

    const float* Pb = P + (size_t)b * (NDIM * NDIM);

    // ---- H = P^T P, staged 32 padded rows of P at a time ----
    for (int chunk = 0; chunk < 8; ++chunk) {
        const float4* src = (const float4*)(Pb + chunk * 8192);
#pragma unroll
        for (int it = 0; it < 4; ++it) {
            int f = it * 512 + t;            // float4 index within chunk
            int k = f >> 6, jq = f & 63;     // row, float4-in-row
            *(float4*)(sm.Ps + k * PS + jq * 4 + ((jq >> 3) << 2)) = src[f];
        }
        __syncthreads();
#pragma unroll 2
        for (int k = 0; k < 32; ++k) {
            const float* row = sm.Ps + k * PS;
            float4 a4 = *(const float4*)(row + voff);        // P[k][4r..4r+3]
            float ar[4] = {a4.x, a4.y, a4.z, a4.w};
#pragma unroll
            for (int jj = 0; jj < 8; ++jj) {
                float4 bq = *(const float4*)(row + c * 36 + jj * 4); // P[k][32c+4jj..]
#pragma unroll
                for (int e = 0; e < 4; ++e) {
                    h[e * 32 + jj * 4 + 0] = fmaf(ar[e], bq.x, h[e * 32 + jj * 4 + 0]);
                    h[e * 32 + jj * 4 + 1] = fmaf(ar[e], bq.y, h[e * 32 + jj * 4 + 1]);
                    h[e * 32 + jj * 4 + 2] = fmaf(ar[e], bq.z, h[e * 32 + jj * 4 + 2]);
                    h[e * 32 + jj * 4 + 3] = fmaf(ar[e], bq.w, h[e * 32 + jj * 4 + 3]);
                }
            }
        }
        __syncthreads();
    }

    float* xa = sm.va;
    float* xb = sm.vb;

    // ---- power iteration, normalization-free (exact 2^-10 rescale/iter;
    //      scale cancels in the Rayleigh quotient) ----
    if (c == 0) *(float4*)(xa + voff) = make_float4(1.f, 1.f, 1.f, 1.f);
    __syncthreads();
    float v4r[4] = {1.f, 1.f, 1.f, 1.f};
    float pw[4];
    for (int it = 0; it < PITERS; ++it) {
        matvec4(h, xa, c, pw);
#pragma unroll
        for (int e = 0; e < 4; ++e) v4r[e] = pw[e] * 0.0009765625f;  // *2^-10
        if (c == 0) *(float4*)(xb + voff) = make_float4(v4r[0], v4r[1], v4r[2], v4r[3]);
        __syncthreads();
        float* tmp = xa; xa = xb; xb = tmp;
    }

    // ---- Rayleigh quotient -> step ----
    matvec4(h, xa, c, pw);                     // Hv (xa holds v4r values)
    float n1 = 0.0f, n2 = 0.0f;
    if (c == 0) {
#pragma unroll
        for (int e = 0; e < 4; ++e) { n1 += v4r[e] * pw[e]; n2 += v4r[e] * v4r[e]; }
    }
#pragma unroll
    for (int off = 1; off < 64; off <<= 1) {
        n1 += __shfl_xor(n1, off);
        n2 += __shfl_xor(n2, off);
    }
    if (lane == 0) { sm.scal[wave] = n1; sm.scal[8 + wave] = n2; }
    __syncthreads();
    float num = 0.0f, den = 0.0f;
#pragma unroll
    for (int w = 0; w < 8; ++w) { num += sm.scal[w]; den += sm.scal[8 + w]; }
    float L = num / den;
    const float step = 1.0f / (1.05f * fmaxf(L, 1e-12f));

    // per-thread constants: b rows 4r..4r+3, SOC radii for constraints 2r, 2r+1
    float4 bi = *(const float4*)(q + b * NDIM + r * 4);
    float2 mu2 = *(const float2*)(mu + b * NCON + r * 2);
    float2 ln2 = *(const float2*)(ln_ + b * NCON + r * 2);
    float rr0 = mu2.x * ln2.x;
    float rr1 = mu2.y * ln2.y;

    // ---- FISTA: l0 = project(0) = 0, y0 = 0, t0 = 1 ----
    if (c == 0) *(float4*)(xa + voff) = make_float4(0.f, 0.f, 0.f, 0.f);
    __syncthreads();
    float li[4] = {0.f, 0.f, 0.f, 0.f};
    float yi[4] = {0.f, 0.f, 0.f, 0.f};
    float tcur = 1.0f;

    for (int it = 0; it < FITERS; ++it) {
        matvec4(h, xa, c, pw);                 // H y
        float z0 = yi[0] - step * (pw[0] + bi.x);
        float z1 = yi[1] - step * (pw[1] + bi.y);
        float z2 = yi[2] - step * (pw[2] + bi.z);
        float z3 = yi[3] - step * (pw[3] + bi.w);
        float nA = sqrtf(z0 * z0 + z1 * z1);
        float sA = (nA > rr0) ? (rr0 / fmaxf(nA, 1e-30f)) : 1.0f;
        float nB = sqrtf(z2 * z2 + z3 * z3);
        float sB = (nB > rr1) ? (rr1 / fmaxf(nB, 1e-30f)) : 1.0f;
        float l0 = z0 * sA, l1 = z1 * sA, l2 = z2 * sB, l3 = z3 * sB;
        float tn = 0.5f * (1.0f + sqrtf(1.0f + 4.0f * tcur * tcur));
        float ratio = (tcur - 1.0f) / tn;
        float y0 = l0 + ratio * (l0 - li[0]);
        float y1 = l1 + ratio * (l1 - li[1]);
        float y2 = l2 + ratio * (l2 - li[2]);
        float y3 = l3 + ratio * (l3 - li[3]);
        li[0] = l0; li[1] = l1; li[2] = l2; li[3] = l3;
        yi[0] = y0; yi[1] = y1; yi[2] = y2; yi[3] = y3;
        tcur = tn;
        if (c == 0) *(float4*)(xb + voff) = make_float4(y0, y1, y2, y3);
        __syncthreads();
        float* tmp = xa; xa = xb; xb = tmp;
    }

    if (c == 0) *(float4*)(out + b * NDIM + r * 4) = make_float4(li[0], li[1], li[2], li[3]);
}

} // namespace

extern "C" void kernel_launch(void* const* d_in, const int* in_sizes, int n_in,
                              void* d_out, int out_size, void* d_ws, size_t ws_size,
                              hipStream_t stream) {
    const float* P   = (const float*)d_in[0];
    const float* q   = (const float*)d_in[1];
    const float* l_n = (const float*)d_in[2];
    const float* mu  = (const float*)d_in[3];
    float* out = (float*)d_out;
    qcqp_fista<<<dim3(512), dim3(512), 0, stream>>>(P, q, l_n, mu, out);
}

// Round 4
// 545.590 us; speedup vs baseline: 1.0540x; 1.0540x over previous
//
#include <hip/hip_runtime.h>
#include <math.h>

// QCQP via FISTA. One 512-thread workgroup per batch; H = P^T P in registers.
// Wave w (0..7) owns cols 32w..32w+31; lane l owns rows 4l..4l+3:
//   h[e*32+j] = H[4l+e][32w+j].
// Matvec: 8 wave-uniform broadcast b128 x-reads + 128 fmac + ONE contiguous
// b128 store of partials into red[parity][w][...]. One barrier. Then lanes
// 0..15 of each wave sum the 8 partials for their SOC pair (cols 32w+2l,
// 32w+2l+1), do the FISTA pointwise update in registers, write the pair to
// wave-private ybuf, and all lanes re-read ybuf (intra-wave, no barrier).

namespace {

constexpr int NDIM = 256;
constexpr int NCON = 128;
constexpr int PITERS = 20;
constexpr int FITERS = 100;

struct Smem {
    float Ps[32 * 256];       // 32 KB P-row staging
    float red[2][8][256];     // 16 KB matvec partials, ping-pong
    float ybuf[8][32];        // 1 KB per-wave y/v vector
    float scal[16];
};

// pw = (partial H x)_{4l..4l+3} over this wave's 32 cols; store to redw.
__device__ __forceinline__ void mv(const float (&h)[128],
                                   const float* __restrict__ xsrc,
                                   float* __restrict__ redw, int l)
{
    float pw0 = 0.f, pw1 = 0.f, pw2 = 0.f, pw3 = 0.f;
#pragma unroll
    for (int jj = 0; jj < 8; ++jj) {
        float4 x4 = *(const float4*)(xsrc + jj * 4);   // wave-uniform broadcast
        pw0 = fmaf(h[0 * 32 + jj * 4 + 0], x4.x, pw0);
        pw0 = fmaf(h[0 * 32 + jj * 4 + 1], x4.y, pw0);
        pw0 = fmaf(h[0 * 32 + jj * 4 + 2], x4.z, pw0);
        pw0 = fmaf(h[0 * 32 + jj * 4 + 3], x4.w, pw0);
        pw1 = fmaf(h[1 * 32 + jj * 4 + 0], x4.x, pw1);
        pw1 = fmaf(h[1 * 32 + jj * 4 + 1], x4.y, pw1);
        pw1 = fmaf(h[1 * 32 + jj * 4 + 2], x4.z, pw1);
        pw1 = fmaf(h[1 * 32 + jj * 4 + 3], x4.w, pw1);
        pw2 = fmaf(h[2 * 32 + jj * 4 + 0], x4.x, pw2);
        pw2 = fmaf(h[2 * 32 + jj * 4 + 1], x4.y, pw2);
        pw2 = fmaf(h[2 * 32 + jj * 4 + 2], x4.z, pw2);
        pw2 = fmaf(h[2 * 32 + jj * 4 + 3], x4.w, pw2);
        pw3 = fmaf(h[3 * 32 + jj * 4 + 0], x4.x, pw3);
        pw3 = fmaf(h[3 * 32 + jj * 4 + 1], x4.y, pw3);
        pw3 = fmaf(h[3 * 32 + jj * 4 + 2], x4.z, pw3);
        pw3 = fmaf(h[3 * 32 + jj * 4 + 3], x4.w, pw3);
    }
    *(float4*)(redw + 4 * l) = make_float4(pw0, pw1, pw2, pw3);  // contiguous 1KB/wave
}

// Sum the 8 per-wave partials for cols (32w+2l, 32w+2l+1); lanes l<16 only.
__device__ __forceinline__ float2 gather_pair(const float (*red8)[256], int w, int l)
{
    float s0 = 0.f, s1 = 0.f;
#pragma unroll
    for (int c2 = 0; c2 < 8; ++c2) {
        float2 p = *(const float2*)&red8[c2][32 * w + 2 * l];
        s0 += p.x; s1 += p.y;
    }
    return make_float2(s0, s1);
}

__global__ __launch_bounds__(512, 2)
void qcqp_fista(const float* __restrict__ P, const float* __restrict__ q,
                const float* __restrict__ ln_, const float* __restrict__ mu,
                float* __restrict__ out)
{
    __shared__ Smem sm;
    const int b = blockIdx.x;
    const int t = threadIdx.x;
    const int w = t >> 6;       // wave id = col block
    const int l = t & 63;       // lane = row block (rows 4l..4l+3)

    float h[128];
#pragma unroll
    for (int i = 0; i < 128; ++i) h[i] = 0.0f;

    const float* Pb = P + (size_t)b * (NDIM * NDIM);

    // ---- H = P^T P, staged 32 rows of P at a time ----
    for (int chunk = 0; chunk < 8; ++chunk) {
        const float4* src = (const float4*)(Pb + chunk * 8192);
        float4* dst = (float4*)sm.Ps;
#pragma unroll
        for (int it = 0; it < 4; ++it)
            dst[it * 512 + t] = src[it * 512 + t];
        __syncthreads();
#pragma unroll 2
        for (int k = 0; k < 32; ++k) {
            const float* row = sm.Ps + k * 256;
            float4 a4 = *(const float4*)(row + 4 * l);     // contiguous b128
            float ar[4] = {a4.x, a4.y, a4.z, a4.w};
#pragma unroll
            for (int jj = 0; jj < 8; ++jj) {
                float4 bq = *(const float4*)(row + 32 * w + 4 * jj);  // broadcast
#pragma unroll
                for (int e = 0; e < 4; ++e) {
                    h[e * 32 + jj * 4 + 0] = fmaf(ar[e], bq.x, h[e * 32 + jj * 4 + 0]);
                    h[e * 32 + jj * 4 + 1] = fmaf(ar[e], bq.y, h[e * 32 + jj * 4 + 1]);
                    h[e * 32 + jj * 4 + 2] = fmaf(ar[e], bq.z, h[e * 32 + jj * 4 + 2]);
                    h[e * 32 + jj * 4 + 3] = fmaf(ar[e], bq.w, h[e * 32 + jj * 4 + 3]);
                }
            }
        }
        __syncthreads();
    }

    // ---- power iteration: v0 = ones; v <- (H v) * 2^-10 (scale cancels in
    //      the Rayleigh quotient; validated R3) ----
    if (l < 32) sm.ybuf[w][l] = 1.0f;           // intra-wave producer
    int phase = 0;
    for (int it = 0; it < PITERS; ++it, ++phase) {
        mv(h, sm.ybuf[w], sm.red[phase & 1][w], l);
        __syncthreads();
        if (l < 16) {
            float2 s = gather_pair(sm.red[phase & 1], w, l);
            *(float2*)&sm.ybuf[w][2 * l] =
                make_float2(s.x * 0.0009765625f, s.y * 0.0009765625f);
        }
    }

    // ---- Rayleigh quotient -> step ----
    mv(h, sm.ybuf[w], sm.red[phase & 1][w], l);
    __syncthreads();
    float n1 = 0.f, n2 = 0.f;
    if (l < 16) {
        float2 hv = gather_pair(sm.red[phase & 1], w, l);
        float v0 = sm.ybuf[w][2 * l + 0];
        float v1 = sm.ybuf[w][2 * l + 1];
        n1 = v0 * hv.x + v1 * hv.y;
        n2 = v0 * v0 + v1 * v1;
    }
#pragma unroll
    for (int off = 1; off < 64; off <<= 1) {
        n1 += __shfl_xor(n1, off);
        n2 += __shfl_xor(n2, off);
    }
    if (l == 0) { sm.scal[w] = n1; sm.scal[8 + w] = n2; }
    __syncthreads();
    float num = 0.f, den = 0.f;
#pragma unroll
    for (int ww = 0; ww < 8; ++ww) { num += sm.scal[ww]; den += sm.scal[8 + ww]; }
    float L = num / den;
    const float step = 1.0f / (1.05f * fmaxf(L, 1e-12f));
    ++phase;

    // ---- FISTA state (lanes l<16 own SOC pair (32w+2l, 32w+2l+1)) ----
    float b0 = 0.f, b1 = 0.f, rr = 0.f;
    if (l < 16) {
        float2 q2 = *(const float2*)(q + b * NDIM + 32 * w + 2 * l);
        b0 = q2.x; b1 = q2.y;
        rr = mu[b * NCON + 16 * w + l] * ln_[b * NCON + 16 * w + l];
    }
    float li0 = 0.f, li1 = 0.f, tcur = 1.0f;
    if (l < 32) sm.ybuf[w][l] = 0.0f;           // y0 = 0, intra-wave

    for (int it = 0; it < FITERS; ++it, ++phase) {
        mv(h, sm.ybuf[w], sm.red[phase & 1][w], l);
        __syncthreads();
        float tn = 0.5f * (1.0f + sqrtf(1.0f + 4.0f * tcur * tcur));
        float ratio = (tcur - 1.0f) / tn;
        tcur = tn;
        if (l < 16) {
            float2 hy = gather_pair(sm.red[phase & 1], w, l);
            float y0 = sm.ybuf[w][2 * l + 0];
            float y1 = sm.ybuf[w][2 * l + 1];
            float z0 = y0 - step * (hy.x + b0);
            float z1 = y1 - step * (hy.y + b1);
            float nrm = sqrtf(z0 * z0 + z1 * z1);
            float scl = (nrm > rr) ? (rr / fmaxf(nrm, 1e-30f)) : 1.0f;
            float l0 = z0 * scl, l1 = z1 * scl;
            float yn0 = l0 + ratio * (l0 - li0);
            float yn1 = l1 + ratio * (l1 - li1);
            li0 = l0; li1 = l1;
            *(float2*)&sm.ybuf[w][2 * l] = make_float2(yn0, yn1);
        }
    }

    if (l < 16)
        *(float2*)(out + b * NDIM + 32 * w + 2 * l) = make_float2(li0, li1);
}

} // namespace

extern "C" void kernel_launch(void* const* d_in, const int* in_sizes, int n_in,
                              void* d_out, int out_size, void* d_ws, size_t ws_size,
                              hipStream_t stream) {
    const float* P   = (const float*)d_in[0];
    const float* q   = (const float*)d_in[1];
    const float* l_n = (const float*)d_in[2];
    const float* mu  = (const float*)d_in[3];
    float* out = (float*)d_out;
    qcqp_fista<<<dim3(512), dim3(512), 0, stream>>>(P, q, l_n, mu, out);
}

// Round 5
// 418.129 us; speedup vs baseline: 1.3753x; 1.3048x over previous
//
#include <hip/hip_runtime.h>
#include <math.h>

// QCQP via FISTA. One 512-thread workgroup per batch.
// H = P^T P computed on MATRIX CORES via bf16 split precision:
//   P = Phi + Plo (RNE splits); H ~= Phi^T Phi + Phi^T Plo + Plo^T Phi.
// For H = P^T P the A-fragment (A[m=lane&15][k=quad*8+j] = P[k][m]) and the
// B-fragment (B[k][n=lane&15] = P[k][n]) are the SAME data -> one fragment
// array per precision, stored fragment-major so all hot reads are b128.
// After the GEMM, acc (MFMA C layout) is remapped to the mv layout via a
// barrier-free intra-wave LDS round trip (wave w owns cols 32w..32w+31 in
// both layouts). Iteration phase identical to R4 (1 barrier/iter, verified).

namespace {

constexpr int NDIM = 256;
constexpr int NCON = 128;
constexpr int PITERS = 20;
constexpr int FITERS = 100;

typedef short bf16x8 __attribute__((ext_vector_type(8)));
typedef float f32x4  __attribute__((ext_vector_type(4)));

struct Smem {
    unsigned short fragHi[16 * 64 * 8];  // 16 KB: [tile][lane] = 8 bf16 (16B)
    unsigned short fragLo[16 * 64 * 8];  // 16 KB
    float Hbuf[8][32 * 36];              // 36.9 KB: per-wave 32-row x 32-col (+pad) slices
    float red[2][8][256];                // 16 KB matvec partials, ping-pong
    float ybuf[8][32];                   // per-wave y/v vector
    float scal[16];
};

__device__ __forceinline__ unsigned short bf16rne(float x) {
    unsigned u = __float_as_uint(x);
    unsigned r = u + 0x7FFFu + ((u >> 16) & 1u);
    return (unsigned short)(r >> 16);
}

// pw = (partial H x)_{4l..4l+3} over this wave's 32 cols; store to redw.
__device__ __forceinline__ void mv(const float (&h)[128],
                                   const float* __restrict__ xsrc,
                                   float* __restrict__ redw, int l)
{
    float pw0 = 0.f, pw1 = 0.f, pw2 = 0.f, pw3 = 0.f;
#pragma unroll
    for (int jj = 0; jj < 8; ++jj) {
        float4 x4 = *(const float4*)(xsrc + jj * 4);   // wave-uniform broadcast
        pw0 = fmaf(h[0 * 32 + jj * 4 + 0], x4.x, pw0);
        pw0 = fmaf(h[0 * 32 + jj * 4 + 1], x4.y, pw0);
        pw0 = fmaf(h[0 * 32 + jj * 4 + 2], x4.z, pw0);
        pw0 = fmaf(h[0 * 32 + jj * 4 + 3], x4.w, pw0);
        pw1 = fmaf(h[1 * 32 + jj * 4 + 0], x4.x, pw1);
        pw1 = fmaf(h[1 * 32 + jj * 4 + 1], x4.y, pw1);
        pw1 = fmaf(h[1 * 32 + jj * 4 + 2], x4.z, pw1);
        pw1 = fmaf(h[1 * 32 + jj * 4 + 3], x4.w, pw1);
        pw2 = fmaf(h[2 * 32 + jj * 4 + 0], x4.x, pw2);
        pw2 = fmaf(h[2 * 32 + jj * 4 + 1], x4.y, pw2);
        pw2 = fmaf(h[2 * 32 + jj * 4 + 2], x4.z, pw2);
        pw2 = fmaf(h[2 * 32 + jj * 4 + 3], x4.w, pw2);
        pw3 = fmaf(h[3 * 32 + jj * 4 + 0], x4.x, pw3);
        pw3 = fmaf(h[3 * 32 + jj * 4 + 1], x4.y, pw3);
        pw3 = fmaf(h[3 * 32 + jj * 4 + 2], x4.z, pw3);
        pw3 = fmaf(h[3 * 32 + jj * 4 + 3], x4.w, pw3);
    }
    *(float4*)(redw + 4 * l) = make_float4(pw0, pw1, pw2, pw3);
}

__device__ __forceinline__ float2 gather_pair(const float (*red8)[256], int w, int l)
{
    float s0 = 0.f, s1 = 0.f;
#pragma unroll
    for (int c2 = 0; c2 < 8; ++c2) {
        float2 p = *(const float2*)&red8[c2][32 * w + 2 * l];
        s0 += p.x; s1 += p.y;
    }
    return make_float2(s0, s1);
}

__global__ __launch_bounds__(512, 2)
void qcqp_fista(const float* __restrict__ P, const float* __restrict__ q,
                const float* __restrict__ ln_, const float* __restrict__ mu,
                float* __restrict__ out)
{
    __shared__ Smem sm;
    const int b = blockIdx.x;
    const int t = threadIdx.x;
    const int w = t >> 6;        // wave id = col block (cols 32w..32w+31)
    const int l = t & 63;

    const float* Pb = P + (size_t)b * (NDIM * NDIM);

    // ================== H = P^T P via bf16-split MFMA ==================
    // Convert roles: thread handles column `col`, k-quads {2*half, 2*half+1}.
    const int col  = t & 255;
    const int half = t >> 8;
    const int tile = col >> 4;

    float pf[16];
    auto load_chunk = [&](int cc) {
#pragma unroll
        for (int g = 0; g < 2; ++g) {
            const int qd = 2 * half + g;
            const float* src = Pb + (cc * 32 + qd * 8) * 256 + col;
#pragma unroll
            for (int j = 0; j < 8; ++j) pf[g * 8 + j] = src[j * 256];
        }
    };

    f32x4 acc[16][2];
#pragma unroll
    for (int i = 0; i < 16; ++i)
#pragma unroll
        for (int j = 0; j < 2; ++j)
#pragma unroll
            for (int e = 0; e < 4; ++e) acc[i][j][e] = 0.0f;

    load_chunk(0);
    for (int c = 0; c < 8; ++c) {
        // convert pf -> hi/lo bf16, write fragment-major (16B per quad-group)
#pragma unroll
        for (int g = 0; g < 2; ++g) {
            const int qd = 2 * half + g;
            unsigned hw[4], lw[4];
#pragma unroll
            for (int jp = 0; jp < 4; ++jp) {
                float f0 = pf[g * 8 + 2 * jp], f1 = pf[g * 8 + 2 * jp + 1];
                unsigned short h0 = bf16rne(f0), h1 = bf16rne(f1);
                float r0 = f0 - __uint_as_float((unsigned)h0 << 16);
                float r1 = f1 - __uint_as_float((unsigned)h1 << 16);
                unsigned short lo0 = bf16rne(r0), lo1 = bf16rne(r1);
                hw[jp] = (unsigned)h0 | ((unsigned)h1 << 16);
                lw[jp] = (unsigned)lo0 | ((unsigned)lo1 << 16);
            }
            const int slot = tile * 64 + ((col & 15) + 16 * qd);
            ((uint4*)sm.fragHi)[slot] = make_uint4(hw[0], hw[1], hw[2], hw[3]);
            ((uint4*)sm.fragLo)[slot] = make_uint4(lw[0], lw[1], lw[2], lw[3]);
        }
        __syncthreads();
        if (c < 7) load_chunk(c + 1);          // prefetch during MFMAs

        const bf16x8* FH = (const bf16x8*)sm.fragHi;
        const bf16x8* FL = (const bf16x8*)sm.fragLo;
        bf16x8 bh0 = FH[(2 * w) * 64 + l];
        bf16x8 bl0 = FL[(2 * w) * 64 + l];
        bf16x8 bh1 = FH[(2 * w + 1) * 64 + l];
        bf16x8 bl1 = FL[(2 * w + 1) * 64 + l];
#pragma unroll
        for (int tr = 0; tr < 16; ++tr) {
            bf16x8 ah = FH[tr * 64 + l];
            bf16x8 al = FL[tr * 64 + l];
            acc[tr][0] = __builtin_amdgcn_mfma_f32_16x16x32_bf16(ah, bh0, acc[tr][0], 0, 0, 0);
            acc[tr][0] = __builtin_amdgcn_mfma_f32_16x16x32_bf16(al, bh0, acc[tr][0], 0, 0, 0);
            acc[tr][0] = __builtin_amdgcn_mfma_f32_16x16x32_bf16(ah, bl0, acc[tr][0], 0, 0, 0);
            acc[tr][1] = __builtin_amdgcn_mfma_f32_16x16x32_bf16(ah, bh1, acc[tr][1], 0, 0, 0);
            acc[tr][1] = __builtin_amdgcn_mfma_f32_16x16x32_bf16(al, bh1, acc[tr][1], 0, 0, 0);
            acc[tr][1] = __builtin_amdgcn_mfma_f32_16x16x32_bf16(ah, bl1, acc[tr][1], 0, 0, 0);
        }
        __syncthreads();                        // MFMA reads done before next writes
    }

    // ---- acc (C layout: row=16tr+4q+reg, col=16(2w+tc)+c16) -> mv layout
    //      h[e*32+j] = H[4l+e][32w+j]. Intra-wave (wave w's cols only). ----
    const int qd4 = (l >> 4) * 4;
    const int c16 = l & 15;
    float* Hw = sm.Hbuf[w];
    float h[128];
#pragma unroll
    for (int rc = 0; rc < 8; ++rc) {           // rows 32rc..32rc+31
#pragma unroll
        for (int tt = 0; tt < 2; ++tt)
#pragma unroll
            for (int tc = 0; tc < 2; ++tc)
#pragma unroll
                for (int reg = 0; reg < 4; ++reg) {
                    int row_local = 16 * tt + qd4 + reg;
                    Hw[row_local * 36 + 16 * tc + c16] = acc[2 * rc + tt][tc][reg];
                }
        // same-wave LDS ops are ordered; no barrier needed
        if ((l >> 3) == rc) {                   // lanes 8rc..8rc+7
            int l2 = l & 7;
#pragma unroll
            for (int e = 0; e < 4; ++e)
#pragma unroll
                for (int jj = 0; jj < 8; ++jj) {
                    float4 v = *(const float4*)&Hw[(4 * l2 + e) * 36 + 4 * jj];
                    h[e * 32 + jj * 4 + 0] = v.x;
                    h[e * 32 + jj * 4 + 1] = v.y;
                    h[e * 32 + jj * 4 + 2] = v.z;
                    h[e * 32 + jj * 4 + 3] = v.w;
                }
        }
    }

    // ================== power iteration (R4-identical) ==================
    if (l < 32) sm.ybuf[w][l] = 1.0f;
    int phase = 0;
    for (int it = 0; it < PITERS; ++it, ++phase) {
        mv(h, sm.ybuf[w], sm.red[phase & 1][w], l);
        __syncthreads();
        if (l < 16) {
            float2 s = gather_pair(sm.red[phase & 1], w, l);
            *(float2*)&sm.ybuf[w][2 * l] =
                make_float2(s.x * 0.0009765625f, s.y * 0.0009765625f);
        }
    }

    // ---- Rayleigh quotient -> step ----
    mv(h, sm.ybuf[w], sm.red[phase & 1][w], l);
    __syncthreads();
    float n1 = 0.f, n2 = 0.f;
    if (l < 16) {
        float2 hv = gather_pair(sm.red[phase & 1], w, l);
        float v0 = sm.ybuf[w][2 * l + 0];
        float v1 = sm.ybuf[w][2 * l + 1];
        n1 = v0 * hv.x + v1 * hv.y;
        n2 = v0 * v0 + v1 * v1;
    }
#pragma unroll
    for (int off = 1; off < 64; off <<= 1) {
        n1 += __shfl_xor(n1, off);
        n2 += __shfl_xor(n2, off);
    }
    if (l == 0) { sm.scal[w] = n1; sm.scal[8 + w] = n2; }
    __syncthreads();
    float num = 0.f, den = 0.f;
#pragma unroll
    for (int ww = 0; ww < 8; ++ww) { num += sm.scal[ww]; den += sm.scal[8 + ww]; }
    float L = num / den;
    const float step = 1.0f / (1.05f * fmaxf(L, 1e-12f));
    ++phase;

    // ---- FISTA (R4-identical) ----
    float b0 = 0.f, b1 = 0.f, rr = 0.f;
    if (l < 16) {
        float2 q2 = *(const float2*)(q + b * NDIM + 32 * w + 2 * l);
        b0 = q2.x; b1 = q2.y;
        rr = mu[b * NCON + 16 * w + l] * ln_[b * NCON + 16 * w + l];
    }
    float li0 = 0.f, li1 = 0.f, tcur = 1.0f;
    if (l < 32) sm.ybuf[w][l] = 0.0f;

    for (int it = 0; it < FITERS; ++it, ++phase) {
        mv(h, sm.ybuf[w], sm.red[phase & 1][w], l);
        __syncthreads();
        float tn = 0.5f * (1.0f + sqrtf(1.0f + 4.0f * tcur * tcur));
        float ratio = (tcur - 1.0f) / tn;
        tcur = tn;
        if (l < 16) {
            float2 hy = gather_pair(sm.red[phase & 1], w, l);
            float y0 = sm.ybuf[w][2 * l + 0];
            float y1 = sm.ybuf[w][2 * l + 1];
            float z0 = y0 - step * (hy.x + b0);
            float z1 = y1 - step * (hy.y + b1);
            float nrm = sqrtf(z0 * z0 + z1 * z1);
            float scl = (nrm > rr) ? (rr / fmaxf(nrm, 1e-30f)) : 1.0f;
            float l0 = z0 * scl, l1 = z1 * scl;
            float yn0 = l0 + ratio * (l0 - li0);
            float yn1 = l1 + ratio * (l1 - li1);
            li0 = l0; li1 = l1;
            *(float2*)&sm.ybuf[w][2 * l] = make_float2(yn0, yn1);
        }
    }

    if (l < 16)
        *(float2*)(out + b * NDIM + 32 * w + 2 * l) = make_float2(li0, li1);
}

} // namespace

extern "C" void kernel_launch(void* const* d_in, const int* in_sizes, int n_in,
                              void* d_out, int out_size, void* d_ws, size_t ws_size,
                              hipStream_t stream) {
    const float* P   = (const float*)d_in[0];
    const float* q   = (const float*)d_in[1];
    const float* l_n = (const float*)d_in[2];
    const float* mu  = (const float*)d_in[3];
    float* out = (float*)d_out;
    qcqp_fista<<<dim3(512), dim3(512), 0, stream>>>(P, q, l_n, mu, out);
}